// Round 18
// baseline (372.727 us; speedup 1.0000x reference)
//
#include <hip/hip_runtime.h>
#include <hip/hip_bf16.h>
#include <stdint.h>

#define NB 8
#define NSEQ 1024
#define DIMM 768
#define NHEADS 12
#define DH 64
#define NQKV 2304
#define ALPHA_ 0.25f
#define SCALE_ 0.125f
#define EPS_ 1e-5f

typedef __bf16 bf16;
typedef bf16 bf16x8 __attribute__((ext_vector_type(8)));
typedef bf16 bf16x4 __attribute__((ext_vector_type(4)));
typedef float f32x4 __attribute__((ext_vector_type(4)));

#define MFMA16(a, b, c) __builtin_amdgcn_mfma_f32_16x16x32_bf16((a), (b), (c), 0, 0, 0)

static __device__ __forceinline__ void load_lds16(const void* gsrc, void* ldst) {
  __builtin_amdgcn_global_load_lds(
      (__attribute__((address_space(1))) void*)gsrc,
      (__attribute__((address_space(3))) void*)ldst, 16, 0, 0);
}

// lgkm-only barrier (in-flight global loads ride across)
#define BAR_LGKM()                                             \
  do {                                                         \
    __builtin_amdgcn_sched_barrier(0);                         \
    asm volatile("s_waitcnt lgkmcnt(0)" ::: "memory");         \
    __builtin_amdgcn_s_barrier();                              \
    __builtin_amdgcn_sched_barrier(0);                         \
  } while (0)

// LDS byte-offset swizzle: XOR bits[6:4] with (row&7) ^ colbyte bits[9:7].
static __device__ __forceinline__ int swz(int row, int cb) {
  return cb ^ ((((row & 7) ^ ((cb >> 7) & 7)) << 4));
}

// ---------------- LayerNorm + bf16 cast: x(8192x768) -> xn bf16 ----------------
__global__ __launch_bounds__(256) void ln_kernel(
    const float* __restrict__ x, const float* __restrict__ gamma,
    const float* __restrict__ beta, bf16* __restrict__ xn) {
  const int row = blockIdx.x * 4 + (threadIdx.x >> 6);
  const int lane = threadIdx.x & 63;
  const float* xr = x + (size_t)row * DIMM;
  float4 v[3];
  float s = 0.f, s2 = 0.f;
#pragma unroll
  for (int c = 0; c < 3; ++c) {
    v[c] = *reinterpret_cast<const float4*>(xr + c * 256 + lane * 4);
    s += v[c].x + v[c].y + v[c].z + v[c].w;
    s2 += v[c].x * v[c].x + v[c].y * v[c].y + v[c].z * v[c].z + v[c].w * v[c].w;
  }
#pragma unroll
  for (int m = 1; m < 64; m <<= 1) {
    s += __shfl_xor(s, m);
    s2 += __shfl_xor(s2, m);
  }
  const float mu = s * (1.f / DIMM);
  const float rstd = rsqrtf(s2 * (1.f / DIMM) - mu * mu + EPS_);
#pragma unroll
  for (int c = 0; c < 3; ++c) {
    const float4 g4 = *reinterpret_cast<const float4*>(gamma + c * 256 + lane * 4);
    const float4 b4 = *reinterpret_cast<const float4*>(beta + c * 256 + lane * 4);
    bf16x4 o;
    o[0] = (bf16)((v[c].x - mu) * rstd * g4.x + b4.x);
    o[1] = (bf16)((v[c].y - mu) * rstd * g4.y + b4.y);
    o[2] = (bf16)((v[c].z - mu) * rstd * g4.z + b4.z);
    o[3] = (bf16)((v[c].w - mu) * rstd * g4.w + b4.w);
    *reinterpret_cast<bf16x4*>(xn + (size_t)row * DIMM + c * 256 + lane * 4) = o;
  }
}

// ------------- transpose + cast: f32 in[R][C] -> bf16 out[C][R] -------------
__global__ __launch_bounds__(256) void tcast_kernel(
    const float* __restrict__ in, bf16* __restrict__ out, int R, int C) {
  __shared__ float tile[32][33];
  const int tx = threadIdx.x & 31, ty = threadIdx.x >> 5;
  const int c0 = blockIdx.x * 32, r0 = blockIdx.y * 32;
#pragma unroll
  for (int i = ty; i < 32; i += 8)
    tile[i][tx] = in[(size_t)(r0 + i) * C + c0 + tx];
  __syncthreads();
#pragma unroll
  for (int i = ty; i < 32; i += 8)
    out[(size_t)(c0 + i) * R + r0 + tx] = (bf16)tile[tx][i];
}

// -- QKV GEMM 128x128: xn(8192x768) @ wT(2304x768 k-major) -> q,k,vT bf16 --
__global__ __launch_bounds__(256) void qkv_gemm(
    const bf16* __restrict__ xn, const bf16* __restrict__ wT,
    bf16* __restrict__ qb, bf16* __restrict__ kb, bf16* __restrict__ vt) {
  __shared__ __align__(16) bf16 As[128 * 32];
  __shared__ __align__(16) bf16 Bs[128 * 32];
  const int tid = threadIdx.x;
  const int wv = tid >> 6, l = tid & 63;
  const int l16 = l & 15, q4 = l >> 4;
  const int wr = wv >> 1, wc = wv & 1;
  const int c0 = blockIdx.x * 128, row0 = blockIdx.y * 128;
  const int sr = tid >> 2, skk = (tid & 3) * 8;
  f32x4 acc[4][4];
#pragma unroll
  for (int m = 0; m < 4; ++m)
#pragma unroll
    for (int n = 0; n < 4; ++n) acc[m][n] = f32x4{0.f, 0.f, 0.f, 0.f};
  for (int k0 = 0; k0 < DIMM; k0 += 32) {
    __syncthreads();
    load_lds16(xn + (size_t)(row0 + sr) * DIMM + k0 + skk, As + tid * 8);
    load_lds16(xn + (size_t)(row0 + 64 + sr) * DIMM + k0 + skk, As + 2048 + tid * 8);
    load_lds16(wT + (size_t)(c0 + sr) * DIMM + k0 + skk, Bs + tid * 8);
    load_lds16(wT + (size_t)(c0 + 64 + sr) * DIMM + k0 + skk, Bs + 2048 + tid * 8);
    __syncthreads();
    bf16x8 a[4], b[4];
#pragma unroll
    for (int m = 0; m < 4; ++m)
      a[m] = *reinterpret_cast<const bf16x8*>(&As[(wr * 64 + m * 16 + l16) * 32 + q4 * 8]);
#pragma unroll
    for (int n = 0; n < 4; ++n)
      b[n] = *reinterpret_cast<const bf16x8*>(&Bs[(wc * 64 + n * 16 + l16) * 32 + q4 * 8]);
#pragma unroll
    for (int m = 0; m < 4; ++m)
#pragma unroll
      for (int n = 0; n < 4; ++n) acc[m][n] = MFMA16(a[m], b[n], acc[m][n]);
  }
  const int sect = c0 / DIMM;  // uniform per block (768 = 6*128)
#pragma unroll
  for (int n = 0; n < 4; ++n) {
    const int gc = c0 + wc * 64 + n * 16 + l16;
    const int head = (gc % DIMM) >> 6;
    const int dd = gc & 63;
#pragma unroll
    for (int m = 0; m < 4; ++m) {
#pragma unroll
      for (int r = 0; r < 4; ++r) {
        const int gm = row0 + wr * 64 + m * 16 + q4 * 4 + r;
        const int b_ = gm >> 10, nn = gm & 1023;
        const size_t bhh = (size_t)b_ * NHEADS + head;
        const bf16 val = (bf16)acc[m][n][r];
        if (sect == 0)      qb[(bhh * NSEQ + nn) * DH + dd] = val;
        else if (sect == 1) kb[(bhh * NSEQ + nn) * DH + dd] = val;
        else                vt[(bhh * DH + dd) * NSEQ + nn] = val;
      }
    }
  }
}

// ---- fused attention (R15 config: NT h/blended via builtins) + XCD swizzle ----
// Flat grid 6144; xcd = id%8 owns bh in [xcd*12, xcd*12+12) so each bh's K/V
// is L2-resident on exactly ONE XCD (was replicated on all 8 -> ~170MB extra
// L3->L2 fabric traffic competing with the h/blended stream).
__global__ __launch_bounds__(256, 4) void attn_kernel(
    const bf16* __restrict__ qb, const bf16* __restrict__ kb,
    const bf16* __restrict__ vt, const float* __restrict__ h,
    float* __restrict__ blended, bf16* __restrict__ attn_out) {
  __shared__ __align__(16) char S_lds[16 * 2176];  // bf16 [16][1088], swizzled
  __shared__ float lred[16];

  const int tid = threadIdx.x;
  const int wv = tid >> 6, l = tid & 63;
  const int l16 = l & 15, q4 = l >> 4;
  // XCD-aware bijective remap: id in [0,6144) -> (bh, i0)
  const int id = blockIdx.x;
  const int xcd = id & 7;
  const int slot = id >> 3;                 // 0..767
  const int bh = xcd * 12 + (slot >> 6);    // 12 bh per XCD
  const int i0 = (slot & 63) * 16;
  const int jb = wv * 256;

  const float* hbase = h + ((size_t)bh << 20);
  float* bbase = blended + ((size_t)bh << 20);

  bf16x8 qT[2];
#pragma unroll
  for (int w2 = 0; w2 < 2; ++w2)
    qT[w2] = *reinterpret_cast<const bf16x8*>(
        qb + ((size_t)bh * NSEQ + i0 + l16) * DH + w2 * 32 + q4 * 8);

  // prefetch h rows wv*4+0,1 (nontemporal; consumed in Phase 2)
  f32x4 hv0[4], hv1[4];
#pragma unroll
  for (int t = 0; t < 4; ++t) {
    hv0[t] = __builtin_nontemporal_load(reinterpret_cast<const f32x4*>(
        hbase + (size_t)(i0 + wv * 4 + 0) * NSEQ + t * 256 + l * 4));
    hv1[t] = __builtin_nontemporal_load(reinterpret_cast<const f32x4*>(
        hbase + (size_t)(i0 + wv * 4 + 1) * NSEQ + t * 256 + l * 4));
  }

  // ---- Phase 1: S(scaled) -> LDS bf16, swizzled ----
  const bf16* kq = kb + ((size_t)bh * NSEQ + jb + l16) * DH + q4 * 8;
  char* srow_w = S_lds + l16 * 2176;
#pragma unroll
  for (int st = 0; st < 4; ++st) {
    f32x4 s[4];
#pragma unroll
    for (int js = 0; js < 4; ++js) s[js] = f32x4{0.f, 0.f, 0.f, 0.f};
#pragma unroll
    for (int js = 0; js < 4; ++js) {
#pragma unroll
      for (int w2 = 0; w2 < 2; ++w2) {
        const bf16x8 kf = *reinterpret_cast<const bf16x8*>(
            kq + (size_t)(st * 64 + js * 16) * DH + w2 * 32);
        s[js] = MFMA16(kf, qT[w2], s[js]);
      }
    }
#pragma unroll
    for (int js = 0; js < 4; ++js) {
      bf16x4 pk;
#pragma unroll
      for (int r = 0; r < 4; ++r) pk[r] = (bf16)(s[js][r] * (ALPHA_ * SCALE_));
      const int cb = (jb + st * 64 + js * 16 + q4 * 4) * 2;
      *reinterpret_cast<bf16x4*>(srow_w + swz(l16, cb)) = pk;
    }
  }

  // prefetch h rows wv*4+2,3 (nontemporal; fly across the barrier)
  f32x4 hv2[4], hv3[4];
#pragma unroll
  for (int t = 0; t < 4; ++t) {
    hv2[t] = __builtin_nontemporal_load(reinterpret_cast<const f32x4*>(
        hbase + (size_t)(i0 + wv * 4 + 2) * NSEQ + t * 256 + l * 4));
    hv3[t] = __builtin_nontemporal_load(reinterpret_cast<const f32x4*>(
        hbase + (size_t)(i0 + wv * 4 + 3) * NSEQ + t * 256 + l * 4));
  }

  BAR_LGKM();  // all waves' S writes visible

  // ---- Phase 2: stream 4 full rows; exact softmax; P overwrites S ----
  auto ROW = [&](int rr, f32x4* hv) {
    const int row = wv * 4 + rr;
    char* srow = S_lds + row * 2176;
    bf16x4 sv[4];
#pragma unroll
    for (int t = 0; t < 4; ++t)
      sv[t] = *reinterpret_cast<const bf16x4*>(srow + swz(row, t * 512 + l * 8));
    f32x4 bl[4];
    float tm = -1e30f;
#pragma unroll
    for (int t = 0; t < 4; ++t) {
      bl[t][0] = fmaf(0.75f, hv[t][0], (float)sv[t][0]);
      bl[t][1] = fmaf(0.75f, hv[t][1], (float)sv[t][1]);
      bl[t][2] = fmaf(0.75f, hv[t][2], (float)sv[t][2]);
      bl[t][3] = fmaf(0.75f, hv[t][3], (float)sv[t][3]);
      __builtin_nontemporal_store(bl[t], reinterpret_cast<f32x4*>(
          bbase + (size_t)(i0 + row) * NSEQ + t * 256 + l * 4));
      tm = fmaxf(tm, fmaxf(fmaxf(bl[t][0], bl[t][1]), fmaxf(bl[t][2], bl[t][3])));
    }
#pragma unroll
    for (int mm = 1; mm < 64; mm <<= 1) tm = fmaxf(tm, __shfl_xor(tm, mm));
    float rs = 0.f;
#pragma unroll
    for (int t = 0; t < 4; ++t) {
      bf16x4 pk;
      const float p0 = __expf(bl[t][0] - tm); rs += p0; pk[0] = (bf16)p0;
      const float p1 = __expf(bl[t][1] - tm); rs += p1; pk[1] = (bf16)p1;
      const float p2 = __expf(bl[t][2] - tm); rs += p2; pk[2] = (bf16)p2;
      const float p3 = __expf(bl[t][3] - tm); rs += p3; pk[3] = (bf16)p3;
      *reinterpret_cast<bf16x4*>(srow + swz(row, t * 512 + l * 8)) = pk;
    }
#pragma unroll
    for (int mm = 1; mm < 64; mm <<= 1) rs += __shfl_xor(rs, mm);
    if (l == 0) lred[row] = rs;
  };
  ROW(0, hv0);
  ROW(1, hv1);
  ROW(2, hv2);
  ROW(3, hv3);

  BAR_LGKM();  // all P + lred visible

  // ---- Phase 3: out(16q x 16d per wave) = P @ V^T ----
  const bf16* vq = vt + ((size_t)bh * DH + wv * 16 + l16) * NSEQ + q4 * 8;
  char* prow = S_lds + l16 * 2176;
  f32x4 a0 = f32x4{0.f, 0.f, 0.f, 0.f}, a1 = a0, a2 = a0, a3 = a0;
#pragma unroll
  for (int ks = 0; ks < 32; ks += 4) {
    const bf16x8 pa0 = *reinterpret_cast<const bf16x8*>(prow + swz(l16, (ks + 0) * 64 + q4 * 16));
    const bf16x8 vf0 = *reinterpret_cast<const bf16x8*>(vq + (ks + 0) * 32);
    a0 = MFMA16(pa0, vf0, a0);
    const bf16x8 pa1 = *reinterpret_cast<const bf16x8*>(prow + swz(l16, (ks + 1) * 64 + q4 * 16));
    const bf16x8 vf1 = *reinterpret_cast<const bf16x8*>(vq + (ks + 1) * 32);
    a1 = MFMA16(pa1, vf1, a1);
    const bf16x8 pa2 = *reinterpret_cast<const bf16x8*>(prow + swz(l16, (ks + 2) * 64 + q4 * 16));
    const bf16x8 vf2 = *reinterpret_cast<const bf16x8*>(vq + (ks + 2) * 32);
    a2 = MFMA16(pa2, vf2, a2);
    const bf16x8 pa3 = *reinterpret_cast<const bf16x8*>(prow + swz(l16, (ks + 3) * 64 + q4 * 16));
    const bf16x8 vf3 = *reinterpret_cast<const bf16x8*>(vq + (ks + 3) * 32);
    a3 = MFMA16(pa3, vf3, a3);
  }
  const f32x4 af = (a0 + a1) + (a2 + a3);
  const int b = bh / NHEADS, head = bh % NHEADS;
#pragma unroll
  for (int r = 0; r < 4; ++r) {
    const int q = q4 * 4 + r;
    attn_out[((size_t)b * NSEQ + i0 + q) * DIMM + head * DH + wv * 16 + l16] =
        (bf16)(af[r] / lred[q]);
  }
}

// -- output projection 128x128: attn_out(8192x768) @ woutT + b_out -> f32 out --
__global__ __launch_bounds__(256) void oproj_gemm(
    const bf16* __restrict__ ain, const bf16* __restrict__ wT,
    const float* __restrict__ bias, float* __restrict__ out) {
  __shared__ __align__(16) bf16 As[128 * 32];
  __shared__ __align__(16) bf16 Bs[128 * 32];
  const int tid = threadIdx.x;
  const int wv = tid >> 6, l = tid & 63;
  const int l16 = l & 15, q4 = l >> 4;
  const int wr = wv >> 1, wc = wv & 1;
  const int c0 = blockIdx.x * 128, row0 = blockIdx.y * 128;
  const int sr = tid >> 2, skk = (tid & 3) * 8;
  f32x4 acc[4][4];
#pragma unroll
  for (int m = 0; m < 4; ++m)
#pragma unroll
    for (int n = 0; n < 4; ++n) acc[m][n] = f32x4{0.f, 0.f, 0.f, 0.f};
  for (int k0 = 0; k0 < DIMM; k0 += 32) {
    __syncthreads();
    load_lds16(ain + (size_t)(row0 + sr) * DIMM + k0 + skk, As + tid * 8);
    load_lds16(ain + (size_t)(row0 + 64 + sr) * DIMM + k0 + skk, As + 2048 + tid * 8);
    load_lds16(wT + (size_t)(c0 + sr) * DIMM + k0 + skk, Bs + tid * 8);
    load_lds16(wT + (size_t)(c0 + 64 + sr) * DIMM + k0 + skk, Bs + 2048 + tid * 8);
    __syncthreads();
    bf16x8 a[4], b[4];
#pragma unroll
    for (int m = 0; m < 4; ++m)
      a[m] = *reinterpret_cast<const bf16x8*>(&As[(wr * 64 + m * 16 + l16) * 32 + q4 * 8]);
#pragma unroll
    for (int n = 0; n < 4; ++n)
      b[n] = *reinterpret_cast<const bf16x8*>(&Bs[(wc * 64 + n * 16 + l16) * 32 + q4 * 8]);
#pragma unroll
    for (int m = 0; m < 4; ++m)
#pragma unroll
      for (int n = 0; n < 4; ++n) acc[m][n] = MFMA16(a[m], b[n], acc[m][n]);
  }
#pragma unroll
  for (int n = 0; n < 4; ++n) {
    const int gc = c0 + wc * 64 + n * 16 + l16;
    const float bv = bias[gc];
#pragma unroll
    for (int m = 0; m < 4; ++m) {
#pragma unroll
      for (int r = 0; r < 4; ++r) {
        const int gm = row0 + wr * 64 + m * 16 + q4 * 4 + r;
        out[(size_t)gm * DIMM + gc] = acc[m][n][r] + bv;
      }
    }
  }
}

extern "C" void kernel_launch(void* const* d_in, const int* in_sizes, int n_in,
                              void* d_out, int out_size, void* d_ws, size_t ws_size,
                              hipStream_t stream) {
  const float* x = (const float*)d_in[0];
  const float* h = (const float*)d_in[1];
  const float* gamma = (const float*)d_in[2];
  const float* beta = (const float*)d_in[3];
  const float* w_qkv = (const float*)d_in[4];
  const float* w_out = (const float*)d_in[5];
  const float* b_out = (const float*)d_in[6];
  float* out = (float*)d_out;
  float* blended = out + (size_t)NB * NSEQ * DIMM;

  char* ws = (char*)d_ws;
  bf16* xn = (bf16*)(ws);                   // 12.6 MB; reused as attn_out after qkv_gemm
  bf16* qb = (bf16*)(ws + 12582912);
  bf16* kb = (bf16*)(ws + 25165824);
  bf16* vt = (bf16*)(ws + 37748736);
  bf16* wqkvT = (bf16*)(ws + 50331648);
  bf16* woutT = (bf16*)(ws + 53870592);

  hipLaunchKernelGGL(ln_kernel, dim3(2048), dim3(256), 0, stream, x, gamma, beta, xn);
  hipLaunchKernelGGL(tcast_kernel, dim3(72, 24), dim3(256), 0, stream, w_qkv, wqkvT, DIMM, NQKV);
  hipLaunchKernelGGL(tcast_kernel, dim3(24, 24), dim3(256), 0, stream, w_out, woutT, DIMM, DIMM);
  hipLaunchKernelGGL(qkv_gemm, dim3(18, 64), dim3(256), 0, stream, xn, wqkvT, qb, kb, vt);
  hipLaunchKernelGGL(attn_kernel, dim3(6144), dim3(256), 0, stream, qb, kb, vt, h, blended, xn);
  hipLaunchKernelGGL(oproj_gemm, dim3(6, 64), dim3(256), 0, stream, xn, woutT, b_out, out);
}

// Round 19
// 365.344 us; speedup vs baseline: 1.0202x; 1.0202x over previous
//
#include <hip/hip_runtime.h>
#include <hip/hip_bf16.h>
#include <stdint.h>

#define NB 8
#define NSEQ 1024
#define DIMM 768
#define NHEADS 12
#define DH 64
#define NQKV 2304
#define ALPHA_ 0.25f
#define SCALE_ 0.125f
#define EPS_ 1e-5f

typedef __bf16 bf16;
typedef bf16 bf16x8 __attribute__((ext_vector_type(8)));
typedef bf16 bf16x4 __attribute__((ext_vector_type(4)));
typedef float f32x4 __attribute__((ext_vector_type(4)));

#define MFMA16(a, b, c) __builtin_amdgcn_mfma_f32_16x16x32_bf16((a), (b), (c), 0, 0, 0)

static __device__ __forceinline__ void load_lds16(const void* gsrc, void* ldst) {
  __builtin_amdgcn_global_load_lds(
      (__attribute__((address_space(1))) void*)gsrc,
      (__attribute__((address_space(3))) void*)ldst, 16, 0, 0);
}

// lgkm-only barrier (in-flight global loads ride across)
#define BAR_LGKM()                                             \
  do {                                                         \
    __builtin_amdgcn_sched_barrier(0);                         \
    asm volatile("s_waitcnt lgkmcnt(0)" ::: "memory");         \
    __builtin_amdgcn_s_barrier();                              \
    __builtin_amdgcn_sched_barrier(0);                         \
  } while (0)

// LDS byte-offset swizzle: XOR bits[6:4] with (row&7) ^ colbyte bits[9:7].
static __device__ __forceinline__ int swz(int row, int cb) {
  return cb ^ ((((row & 7) ^ ((cb >> 7) & 7)) << 4));
}

// ---------------- LayerNorm + bf16 cast: x(8192x768) -> xn bf16 ----------------
__global__ __launch_bounds__(256) void ln_kernel(
    const float* __restrict__ x, const float* __restrict__ gamma,
    const float* __restrict__ beta, bf16* __restrict__ xn) {
  const int row = blockIdx.x * 4 + (threadIdx.x >> 6);
  const int lane = threadIdx.x & 63;
  const float* xr = x + (size_t)row * DIMM;
  float4 v[3];
  float s = 0.f, s2 = 0.f;
#pragma unroll
  for (int c = 0; c < 3; ++c) {
    v[c] = *reinterpret_cast<const float4*>(xr + c * 256 + lane * 4);
    s += v[c].x + v[c].y + v[c].z + v[c].w;
    s2 += v[c].x * v[c].x + v[c].y * v[c].y + v[c].z * v[c].z + v[c].w * v[c].w;
  }
#pragma unroll
  for (int m = 1; m < 64; m <<= 1) {
    s += __shfl_xor(s, m);
    s2 += __shfl_xor(s2, m);
  }
  const float mu = s * (1.f / DIMM);
  const float rstd = rsqrtf(s2 * (1.f / DIMM) - mu * mu + EPS_);
#pragma unroll
  for (int c = 0; c < 3; ++c) {
    const float4 g4 = *reinterpret_cast<const float4*>(gamma + c * 256 + lane * 4);
    const float4 b4 = *reinterpret_cast<const float4*>(beta + c * 256 + lane * 4);
    bf16x4 o;
    o[0] = (bf16)((v[c].x - mu) * rstd * g4.x + b4.x);
    o[1] = (bf16)((v[c].y - mu) * rstd * g4.y + b4.y);
    o[2] = (bf16)((v[c].z - mu) * rstd * g4.z + b4.z);
    o[3] = (bf16)((v[c].w - mu) * rstd * g4.w + b4.w);
    *reinterpret_cast<bf16x4*>(xn + (size_t)row * DIMM + c * 256 + lane * 4) = o;
  }
}

// ------------- transpose + cast: f32 in[R][C] -> bf16 out[C][R] -------------
__global__ __launch_bounds__(256) void tcast_kernel(
    const float* __restrict__ in, bf16* __restrict__ out, int R, int C) {
  __shared__ float tile[32][33];
  const int tx = threadIdx.x & 31, ty = threadIdx.x >> 5;
  const int c0 = blockIdx.x * 32, r0 = blockIdx.y * 32;
#pragma unroll
  for (int i = ty; i < 32; i += 8)
    tile[i][tx] = in[(size_t)(r0 + i) * C + c0 + tx];
  __syncthreads();
#pragma unroll
  for (int i = ty; i < 32; i += 8)
    out[(size_t)(c0 + i) * R + r0 + tx] = (bf16)tile[tx][i];
}

// -- QKV GEMM 128x128: xn(8192x768) @ wT(2304x768 k-major) -> q,k,vT bf16 --
__global__ __launch_bounds__(256) void qkv_gemm(
    const bf16* __restrict__ xn, const bf16* __restrict__ wT,
    bf16* __restrict__ qb, bf16* __restrict__ kb, bf16* __restrict__ vt) {
  __shared__ __align__(16) bf16 As[128 * 32];
  __shared__ __align__(16) bf16 Bs[128 * 32];
  const int tid = threadIdx.x;
  const int wv = tid >> 6, l = tid & 63;
  const int l16 = l & 15, q4 = l >> 4;
  const int wr = wv >> 1, wc = wv & 1;
  const int c0 = blockIdx.x * 128, row0 = blockIdx.y * 128;
  const int sr = tid >> 2, skk = (tid & 3) * 8;
  f32x4 acc[4][4];
#pragma unroll
  for (int m = 0; m < 4; ++m)
#pragma unroll
    for (int n = 0; n < 4; ++n) acc[m][n] = f32x4{0.f, 0.f, 0.f, 0.f};
  for (int k0 = 0; k0 < DIMM; k0 += 32) {
    __syncthreads();
    load_lds16(xn + (size_t)(row0 + sr) * DIMM + k0 + skk, As + tid * 8);
    load_lds16(xn + (size_t)(row0 + 64 + sr) * DIMM + k0 + skk, As + 2048 + tid * 8);
    load_lds16(wT + (size_t)(c0 + sr) * DIMM + k0 + skk, Bs + tid * 8);
    load_lds16(wT + (size_t)(c0 + 64 + sr) * DIMM + k0 + skk, Bs + 2048 + tid * 8);
    __syncthreads();
    bf16x8 a[4], b[4];
#pragma unroll
    for (int m = 0; m < 4; ++m)
      a[m] = *reinterpret_cast<const bf16x8*>(&As[(wr * 64 + m * 16 + l16) * 32 + q4 * 8]);
#pragma unroll
    for (int n = 0; n < 4; ++n)
      b[n] = *reinterpret_cast<const bf16x8*>(&Bs[(wc * 64 + n * 16 + l16) * 32 + q4 * 8]);
#pragma unroll
    for (int m = 0; m < 4; ++m)
#pragma unroll
      for (int n = 0; n < 4; ++n) acc[m][n] = MFMA16(a[m], b[n], acc[m][n]);
  }
  const int sect = c0 / DIMM;  // uniform per block (768 = 6*128)
#pragma unroll
  for (int n = 0; n < 4; ++n) {
    const int gc = c0 + wc * 64 + n * 16 + l16;
    const int head = (gc % DIMM) >> 6;
    const int dd = gc & 63;
#pragma unroll
    for (int m = 0; m < 4; ++m) {
#pragma unroll
      for (int r = 0; r < 4; ++r) {
        const int gm = row0 + wr * 64 + m * 16 + q4 * 4 + r;
        const int b_ = gm >> 10, nn = gm & 1023;
        const size_t bhh = (size_t)b_ * NHEADS + head;
        const bf16 val = (bf16)acc[m][n][r];
        if (sect == 0)      qb[(bhh * NSEQ + nn) * DH + dd] = val;
        else if (sect == 1) kb[(bhh * NSEQ + nn) * DH + dd] = val;
        else                vt[(bhh * DH + dd) * NSEQ + nn] = val;
      }
    }
  }
}

// -------- fused attention (R15 best config: NT h/blended via builtins) --------
// 3-phase: P1 S=QK^T (swapped operands) -> bf16 swizzled LDS [16][1088];
// P2 wave owns 4 full rows: NT h read / NT blended write in contiguous 1KB
// bursts, EXACT per-row softmax; P overwrites S. P3 PV from LDS x V^T (L2).
__global__ __launch_bounds__(256, 4) void attn_kernel(
    const bf16* __restrict__ qb, const bf16* __restrict__ kb,
    const bf16* __restrict__ vt, const float* __restrict__ h,
    float* __restrict__ blended, bf16* __restrict__ attn_out) {
  __shared__ __align__(16) char S_lds[16 * 2176];  // bf16 [16][1088], swizzled
  __shared__ float lred[16];

  const int tid = threadIdx.x;
  const int wv = tid >> 6, l = tid & 63;
  const int l16 = l & 15, q4 = l >> 4;
  const int i0 = blockIdx.x * 16;
  const int bh = blockIdx.y;
  const int jb = wv * 256;

  const float* hbase = h + ((size_t)bh << 20);
  float* bbase = blended + ((size_t)bh << 20);

  bf16x8 qT[2];
#pragma unroll
  for (int w2 = 0; w2 < 2; ++w2)
    qT[w2] = *reinterpret_cast<const bf16x8*>(
        qb + ((size_t)bh * NSEQ + i0 + l16) * DH + w2 * 32 + q4 * 8);

  // prefetch h rows wv*4+0,1 (nontemporal; consumed in Phase 2)
  f32x4 hv0[4], hv1[4];
#pragma unroll
  for (int t = 0; t < 4; ++t) {
    hv0[t] = __builtin_nontemporal_load(reinterpret_cast<const f32x4*>(
        hbase + (size_t)(i0 + wv * 4 + 0) * NSEQ + t * 256 + l * 4));
    hv1[t] = __builtin_nontemporal_load(reinterpret_cast<const f32x4*>(
        hbase + (size_t)(i0 + wv * 4 + 1) * NSEQ + t * 256 + l * 4));
  }

  // ---- Phase 1: S(scaled) -> LDS bf16, swizzled ----
  const bf16* kq = kb + ((size_t)bh * NSEQ + jb + l16) * DH + q4 * 8;
  char* srow_w = S_lds + l16 * 2176;
#pragma unroll
  for (int st = 0; st < 4; ++st) {
    f32x4 s[4];
#pragma unroll
    for (int js = 0; js < 4; ++js) s[js] = f32x4{0.f, 0.f, 0.f, 0.f};
#pragma unroll
    for (int js = 0; js < 4; ++js) {
#pragma unroll
      for (int w2 = 0; w2 < 2; ++w2) {
        const bf16x8 kf = *reinterpret_cast<const bf16x8*>(
            kq + (size_t)(st * 64 + js * 16) * DH + w2 * 32);
        s[js] = MFMA16(kf, qT[w2], s[js]);
      }
    }
#pragma unroll
    for (int js = 0; js < 4; ++js) {
      bf16x4 pk;
#pragma unroll
      for (int r = 0; r < 4; ++r) pk[r] = (bf16)(s[js][r] * (ALPHA_ * SCALE_));
      const int cb = (jb + st * 64 + js * 16 + q4 * 4) * 2;
      *reinterpret_cast<bf16x4*>(srow_w + swz(l16, cb)) = pk;
    }
  }

  // prefetch h rows wv*4+2,3 (nontemporal; fly across the barrier)
  f32x4 hv2[4], hv3[4];
#pragma unroll
  for (int t = 0; t < 4; ++t) {
    hv2[t] = __builtin_nontemporal_load(reinterpret_cast<const f32x4*>(
        hbase + (size_t)(i0 + wv * 4 + 2) * NSEQ + t * 256 + l * 4));
    hv3[t] = __builtin_nontemporal_load(reinterpret_cast<const f32x4*>(
        hbase + (size_t)(i0 + wv * 4 + 3) * NSEQ + t * 256 + l * 4));
  }

  BAR_LGKM();  // all waves' S writes visible

  // ---- Phase 2: stream 4 full rows; exact softmax; P overwrites S ----
  auto ROW = [&](int rr, f32x4* hv) {
    const int row = wv * 4 + rr;
    char* srow = S_lds + row * 2176;
    bf16x4 sv[4];
#pragma unroll
    for (int t = 0; t < 4; ++t)
      sv[t] = *reinterpret_cast<const bf16x4*>(srow + swz(row, t * 512 + l * 8));
    f32x4 bl[4];
    float tm = -1e30f;
#pragma unroll
    for (int t = 0; t < 4; ++t) {
      bl[t][0] = fmaf(0.75f, hv[t][0], (float)sv[t][0]);
      bl[t][1] = fmaf(0.75f, hv[t][1], (float)sv[t][1]);
      bl[t][2] = fmaf(0.75f, hv[t][2], (float)sv[t][2]);
      bl[t][3] = fmaf(0.75f, hv[t][3], (float)sv[t][3]);
      __builtin_nontemporal_store(bl[t], reinterpret_cast<f32x4*>(
          bbase + (size_t)(i0 + row) * NSEQ + t * 256 + l * 4));
      tm = fmaxf(tm, fmaxf(fmaxf(bl[t][0], bl[t][1]), fmaxf(bl[t][2], bl[t][3])));
    }
#pragma unroll
    for (int mm = 1; mm < 64; mm <<= 1) tm = fmaxf(tm, __shfl_xor(tm, mm));
    float rs = 0.f;
#pragma unroll
    for (int t = 0; t < 4; ++t) {
      bf16x4 pk;
      const float p0 = __expf(bl[t][0] - tm); rs += p0; pk[0] = (bf16)p0;
      const float p1 = __expf(bl[t][1] - tm); rs += p1; pk[1] = (bf16)p1;
      const float p2 = __expf(bl[t][2] - tm); rs += p2; pk[2] = (bf16)p2;
      const float p3 = __expf(bl[t][3] - tm); rs += p3; pk[3] = (bf16)p3;
      *reinterpret_cast<bf16x4*>(srow + swz(row, t * 512 + l * 8)) = pk;
    }
#pragma unroll
    for (int mm = 1; mm < 64; mm <<= 1) rs += __shfl_xor(rs, mm);
    if (l == 0) lred[row] = rs;
  };
  ROW(0, hv0);
  ROW(1, hv1);
  ROW(2, hv2);
  ROW(3, hv3);

  BAR_LGKM();  // all P + lred visible

  // ---- Phase 3: out(16q x 16d per wave) = P @ V^T ----
  const bf16* vq = vt + ((size_t)bh * DH + wv * 16 + l16) * NSEQ + q4 * 8;
  char* prow = S_lds + l16 * 2176;
  f32x4 a0 = f32x4{0.f, 0.f, 0.f, 0.f}, a1 = a0, a2 = a0, a3 = a0;
#pragma unroll
  for (int ks = 0; ks < 32; ks += 4) {
    const bf16x8 pa0 = *reinterpret_cast<const bf16x8*>(prow + swz(l16, (ks + 0) * 64 + q4 * 16));
    const bf16x8 vf0 = *reinterpret_cast<const bf16x8*>(vq + (ks + 0) * 32);
    a0 = MFMA16(pa0, vf0, a0);
    const bf16x8 pa1 = *reinterpret_cast<const bf16x8*>(prow + swz(l16, (ks + 1) * 64 + q4 * 16));
    const bf16x8 vf1 = *reinterpret_cast<const bf16x8*>(vq + (ks + 1) * 32);
    a1 = MFMA16(pa1, vf1, a1);
    const bf16x8 pa2 = *reinterpret_cast<const bf16x8*>(prow + swz(l16, (ks + 2) * 64 + q4 * 16));
    const bf16x8 vf2 = *reinterpret_cast<const bf16x8*>(vq + (ks + 2) * 32);
    a2 = MFMA16(pa2, vf2, a2);
    const bf16x8 pa3 = *reinterpret_cast<const bf16x8*>(prow + swz(l16, (ks + 3) * 64 + q4 * 16));
    const bf16x8 vf3 = *reinterpret_cast<const bf16x8*>(vq + (ks + 3) * 32);
    a3 = MFMA16(pa3, vf3, a3);
  }
  const f32x4 af = (a0 + a1) + (a2 + a3);
  const int b = bh / NHEADS, head = bh % NHEADS;
#pragma unroll
  for (int r = 0; r < 4; ++r) {
    const int q = q4 * 4 + r;
    attn_out[((size_t)b * NSEQ + i0 + q) * DIMM + head * DH + wv * 16 + l16] =
        (bf16)(af[r] / lred[q]);
  }
}

// -- output projection 128x128: attn_out(8192x768) @ woutT + b_out -> f32 out --
__global__ __launch_bounds__(256) void oproj_gemm(
    const bf16* __restrict__ ain, const bf16* __restrict__ wT,
    const float* __restrict__ bias, float* __restrict__ out) {
  __shared__ __align__(16) bf16 As[128 * 32];
  __shared__ __align__(16) bf16 Bs[128 * 32];
  const int tid = threadIdx.x;
  const int wv = tid >> 6, l = tid & 63;
  const int l16 = l & 15, q4 = l >> 4;
  const int wr = wv >> 1, wc = wv & 1;
  const int c0 = blockIdx.x * 128, row0 = blockIdx.y * 128;
  const int sr = tid >> 2, skk = (tid & 3) * 8;
  f32x4 acc[4][4];
#pragma unroll
  for (int m = 0; m < 4; ++m)
#pragma unroll
    for (int n = 0; n < 4; ++n) acc[m][n] = f32x4{0.f, 0.f, 0.f, 0.f};
  for (int k0 = 0; k0 < DIMM; k0 += 32) {
    __syncthreads();
    load_lds16(ain + (size_t)(row0 + sr) * DIMM + k0 + skk, As + tid * 8);
    load_lds16(ain + (size_t)(row0 + 64 + sr) * DIMM + k0 + skk, As + 2048 + tid * 8);
    load_lds16(wT + (size_t)(c0 + sr) * DIMM + k0 + skk, Bs + tid * 8);
    load_lds16(wT + (size_t)(c0 + 64 + sr) * DIMM + k0 + skk, Bs + 2048 + tid * 8);
    __syncthreads();
    bf16x8 a[4], b[4];
#pragma unroll
    for (int m = 0; m < 4; ++m)
      a[m] = *reinterpret_cast<const bf16x8*>(&As[(wr * 64 + m * 16 + l16) * 32 + q4 * 8]);
#pragma unroll
    for (int n = 0; n < 4; ++n)
      b[n] = *reinterpret_cast<const bf16x8*>(&Bs[(wc * 64 + n * 16 + l16) * 32 + q4 * 8]);
#pragma unroll
    for (int m = 0; m < 4; ++m)
#pragma unroll
      for (int n = 0; n < 4; ++n) acc[m][n] = MFMA16(a[m], b[n], acc[m][n]);
  }
#pragma unroll
  for (int n = 0; n < 4; ++n) {
    const int gc = c0 + wc * 64 + n * 16 + l16;
    const float bv = bias[gc];
#pragma unroll
    for (int m = 0; m < 4; ++m) {
#pragma unroll
      for (int r = 0; r < 4; ++r) {
        const int gm = row0 + wr * 64 + m * 16 + q4 * 4 + r;
        out[(size_t)gm * DIMM + gc] = acc[m][n][r] + bv;
      }
    }
  }
}

extern "C" void kernel_launch(void* const* d_in, const int* in_sizes, int n_in,
                              void* d_out, int out_size, void* d_ws, size_t ws_size,
                              hipStream_t stream) {
  const float* x = (const float*)d_in[0];
  const float* h = (const float*)d_in[1];
  const float* gamma = (const float*)d_in[2];
  const float* beta = (const float*)d_in[3];
  const float* w_qkv = (const float*)d_in[4];
  const float* w_out = (const float*)d_in[5];
  const float* b_out = (const float*)d_in[6];
  float* out = (float*)d_out;
  float* blended = out + (size_t)NB * NSEQ * DIMM;

  char* ws = (char*)d_ws;
  bf16* xn = (bf16*)(ws);                   // 12.6 MB; reused as attn_out after qkv_gemm
  bf16* qb = (bf16*)(ws + 12582912);
  bf16* kb = (bf16*)(ws + 25165824);
  bf16* vt = (bf16*)(ws + 37748736);
  bf16* wqkvT = (bf16*)(ws + 50331648);
  bf16* woutT = (bf16*)(ws + 53870592);

  hipLaunchKernelGGL(ln_kernel, dim3(2048), dim3(256), 0, stream, x, gamma, beta, xn);
  hipLaunchKernelGGL(tcast_kernel, dim3(72, 24), dim3(256), 0, stream, w_qkv, wqkvT, DIMM, NQKV);
  hipLaunchKernelGGL(tcast_kernel, dim3(24, 24), dim3(256), 0, stream, w_out, woutT, DIMM, DIMM);
  hipLaunchKernelGGL(qkv_gemm, dim3(18, 64), dim3(256), 0, stream, xn, wqkvT, qb, kb, vt);
  hipLaunchKernelGGL(attn_kernel, dim3(64, 96), dim3(256), 0, stream, qb, kb, vt, h, blended, xn);
  hipLaunchKernelGGL(oproj_gemm, dim3(6, 64), dim3(256), 0, stream, xn, woutT, b_out, out);
}